// Round 7
// baseline (92.882 us; speedup 1.0000x reference)
//
#include <hip/hip_runtime.h>

// KAN conv as densified GEMM: out[px,f] = sum_k Basis[px,k] * W[k,f]
//   px = (b,p,q) 8192, f = 64, K = 16 chunks x 640:
//   chunk kl in [0,576): spline (cl*144 + ij*16 + g), taps (1-fr)@idx, fr@idx+1
//   chunk kl in [576,640): silu at cl*16 + ij (ij<9), rest zero-pad (W rows 0)
// W pre-swizzled to MFMA 16x16x32 f16 B-fragment order. Basis built in LDS:
// each event builds its full 16-f16 g-row in _Float16 vector registers
// (one-hot pair via unrolled selects) and stores it as two v8h (ds_write_b128)
// -- full-row overwrite, no self-clearing, no per-chunk zeroing, and all LDS
// stores stay in the _Float16 type domain (no int-typed punning).
// x prefetched a chunk ahead. 3-way K-split -> partials + combine.

typedef _Float16 v8h __attribute__((ext_vector_type(8)));
typedef float    v4f __attribute__((ext_vector_type(4)));

#define NSLOT   655360            // 10240 * 64 f16
#define PARTOFF 1310720           // bytes: wsw size
#define NPART   524288            // floats per partial (8192*64)

// Wsw slot ((ks*4+nt)*64+lane)*8+j = W[k=ks*32+(lane>>4)*8+j][f=nt*16+(lane&15)]
__global__ __launch_bounds__(256) void prep_wsw(const float* __restrict__ cp,
                                                const float* __restrict__ w1,
                                                const float* __restrict__ w2,
                                                _Float16* __restrict__ wsw) {
    int tid  = blockIdx.x * 256 + threadIdx.x;
    int j    = tid & 7;
    int lane = (tid >> 3) & 63;
    int rest = tid >> 9;
    int nt   = rest & 3;
    int ks   = rest >> 2;
    int k    = ks * 32 + ((lane >> 4) << 3) + j;
    int f    = (nt << 4) + (lane & 15);
    int chunk = k / 640;
    int kl    = k - chunk * 640;
    float val = 0.f;
    if (kl < 576) {
        int c = (chunk << 2) + kl / 144;
        int r = kl % 144;                       // ij*16 + g
        val = w1[f * 576 + c * 9 + (r >> 4)] * cp[f * 9216 + c * 144 + r];
    } else {
        int i2 = kl - 576;
        int ij = i2 & 15;
        if (ij < 9) {
            int c = (chunk << 2) + (i2 >> 4);
            val = w2[f * 576 + c * 9 + ij];
        }
    }
    wsw[tid] = (_Float16)val;
}

// grid 768: kh = blk>>8 (chunk range {0-5,6-10,11-15}), rowid = blk&255 = (b,p).
// WG = 32 px (one image row). 4 waves split each chunk's 20 ksteps (5 each);
// each wave holds the full 32x64 fp32 accumulator; LDS reduce at the end.
__global__ __launch_bounds__(256, 3) void kan_mfma(const float* __restrict__ x,
                                                   const _Float16* __restrict__ wsw,
                                                   float* __restrict__ part) {
    __shared__ __align__(16) char smem[41472];
    _Float16* sb  = (_Float16*)smem;       // [32][648] f16 basis (stride 648)
    float*    red = (float*)smem;          // [4][32][65] f32 reduce, aliases sb

    int blk   = blockIdx.x;
    int kh    = blk >> 8;
    int rowid = blk & 255;
    int b = rowid >> 5, p = rowid & 31;
    int t = threadIdx.x, wv = t >> 6, lane = t & 63;
    int m = lane & 15, kq = lane >> 4;

    const int chs[4] = {0, 6, 11, 16};
    int ch0 = chs[kh], ch1 = chs[kh + 1];

    // one-time zero (covers silu holes / pad; spline rows fully rewritten per chunk)
    v4f z4 = (v4f){0.f, 0.f, 0.f, 0.f};
    for (int i4 = t; i4 < 2592; i4 += 256) ((v4f*)sb)[i4] = z4;

    // ---- hoist per-thread event geometry (chunk-invariant) ----
    const float* xb = x + (size_t)b * 65536;
    int  off0[5], sbF[5], sil[5];
    bool okv[5];
#pragma unroll
    for (int it = 0; it < 5; ++it) {
        int e  = t + it * 256;
        int ec = e < 1152 ? e : 0;           // dummy for inactive slots
        int px = ec / 36;
        int r  = ec - px * 36;
        int cl = r / 9;
        int ij = r - cl * 9;
        int di = ij / 3;
        int dj = ij - di * 3;
        int row = p + di - 1;
        int col = px + dj - 1;
        okv[it]  = ((unsigned)row < 32u) && ((unsigned)col < 32u) && (e < 1152);
        off0[it] = okv[it] ? ((row * 32 + col) * 64 + cl) : 0;
        sbF[it]  = px * 648 + cl * 144 + ij * 16;     // f16 index of 16-wide g-row
        sil[it]  = px * 648 + 576 + cl * 16 + ij;     // f16 index of silu slot
    }

    v4f acc[2][4];
#pragma unroll
    for (int i = 0; i < 2; ++i)
#pragma unroll
        for (int n = 0; n < 4; ++n) acc[i][n] = z4;

    // prologue prefetch for first chunk
    float vbuf[5];
#pragma unroll
    for (int it = 0; it < 5; ++it)
        vbuf[it] = okv[it] ? xb[off0[it] + ch0 * 4] : 0.f;

    __syncthreads();   // zero done

    for (int gch = ch0; gch < ch1; ++gch) {
        // ---- scatter: build 16-f16 one-hot-pair row in v8h regs, 2x b128 ----
#pragma unroll
        for (int it = 0; it < 5; ++it) {
            if (t + it * 256 < 1152) {       // wave-uniform (boundary at t=128)
                float v  = vbuf[it];
                float xc = fminf(fmaxf(v, -1.f), 1.f);
                float tt = (xc + 1.f) * 7.5f;
                int idx  = (int)tt;
                if (idx > 14) idx = 14;
                float fr = tt - (float)idx;
                float sv = v * __builtin_amdgcn_rcpf(1.f + __expf(-v));
                _Float16 hg = (_Float16)(1.f - fr);   // tap at g = idx
                _Float16 hf = (_Float16)fr;           // tap at g = idx+1
                _Float16 hz = (_Float16)0.f;
                v8h row0, row1;
#pragma unroll
                for (int g = 0; g < 8; ++g)
                    row0[g] = (g == idx) ? hg : ((g == idx + 1) ? hf : hz);
#pragma unroll
                for (int g = 8; g < 16; ++g)
                    row1[g - 8] = (g == idx) ? hg : ((g == idx + 1) ? hf : hz);
                *(v8h*)(sb + sbF[it])     = row0;
                *(v8h*)(sb + sbF[it] + 8) = row1;
                sb[sil[it]] = (_Float16)sv;
            }
        }
        // ---- prefetch next chunk's x (latency overlaps barrier + MFMA) ----
        if (gch + 1 < ch1) {
#pragma unroll
            for (int it = 0; it < 5; ++it)
                vbuf[it] = okv[it] ? xb[off0[it] + (gch + 1) * 4] : 0.f;
        }
        __syncthreads();
        // ---- MFMA: 20 ksteps, this wave takes 5 ----
        const _Float16* ap0 = sb + m * 648 + (wv * 5) * 32 + kq * 8;
        const v8h* bp = (const v8h*)wsw + ((size_t)gch * 20 + wv * 5) * 256 + lane;
#pragma unroll
        for (int s = 0; s < 5; ++s) {
            v8h a0 = *(const v8h*)(ap0 + s * 32);
            v8h a1 = *(const v8h*)(ap0 + s * 32 + 16 * 648);
            v8h b0 = bp[s * 256];
            v8h b1 = bp[s * 256 + 64];
            v8h b2 = bp[s * 256 + 128];
            v8h b3 = bp[s * 256 + 192];
            acc[0][0] = __builtin_amdgcn_mfma_f32_16x16x32_f16(a0, b0, acc[0][0], 0, 0, 0);
            acc[0][1] = __builtin_amdgcn_mfma_f32_16x16x32_f16(a0, b1, acc[0][1], 0, 0, 0);
            acc[0][2] = __builtin_amdgcn_mfma_f32_16x16x32_f16(a0, b2, acc[0][2], 0, 0, 0);
            acc[0][3] = __builtin_amdgcn_mfma_f32_16x16x32_f16(a0, b3, acc[0][3], 0, 0, 0);
            acc[1][0] = __builtin_amdgcn_mfma_f32_16x16x32_f16(a1, b0, acc[1][0], 0, 0, 0);
            acc[1][1] = __builtin_amdgcn_mfma_f32_16x16x32_f16(a1, b1, acc[1][1], 0, 0, 0);
            acc[1][2] = __builtin_amdgcn_mfma_f32_16x16x32_f16(a1, b2, acc[1][2], 0, 0, 0);
            acc[1][3] = __builtin_amdgcn_mfma_f32_16x16x32_f16(a1, b3, acc[1][3], 0, 0, 0);
        }
        __syncthreads();
    }

    // ---- 4-wave LDS reduction, then plain coalesced stores to partial ----
#pragma unroll
    for (int mt = 0; mt < 2; ++mt)
#pragma unroll
        for (int nt = 0; nt < 4; ++nt)
#pragma unroll
            for (int r = 0; r < 4; ++r)
                red[wv * 2080 + (mt * 16 + kq * 4 + r) * 65 + nt * 16 + m] = acc[mt][nt][r];
    __syncthreads();
    int f = t & 63, pxg = t >> 6;
    float* op = part + (size_t)kh * NPART + rowid * 2048 + f;
#pragma unroll
    for (int i = 0; i < 8; ++i) {
        int px = pxg * 8 + i;
        float s = red[px * 65 + f] + red[2080 + px * 65 + f]
                + red[4160 + px * 65 + f] + red[6240 + px * 65 + f];
        op[px * 64] = s;
    }
}

__global__ __launch_bounds__(256) void combine(const float* __restrict__ part,
                                               float* __restrict__ out) {
    int i = blockIdx.x * 256 + threadIdx.x;
    v4f a = ((const v4f*)part)[i];
    v4f b = ((const v4f*)(part + NPART))[i];
    v4f c = ((const v4f*)(part + 2 * NPART))[i];
    ((v4f*)out)[i] = a + b + c;
}

extern "C" void kernel_launch(void* const* d_in, const int* in_sizes, int n_in,
                              void* d_out, int out_size, void* d_ws, size_t ws_size,
                              hipStream_t stream) {
    const float* x  = (const float*)d_in[0];
    const float* cp = (const float*)d_in[1];
    const float* w1 = (const float*)d_in[2];
    const float* w2 = (const float*)d_in[3];
    _Float16* wsw = (_Float16*)d_ws;                       // 1.31 MB
    float*    prt = (float*)((char*)d_ws + PARTOFF);       // 3 x 2 MB partials

    prep_wsw<<<NSLOT / 256, 256, 0, stream>>>(cp, w1, w2, wsw);
    kan_mfma<<<768, 256, 0, stream>>>(x, wsw, prt);
    combine<<<512, 256, 0, stream>>>(prt, (float*)d_out);
}